// Round 1
// baseline (3657.467 us; speedup 1.0000x reference)
//
#include <hip/hip_runtime.h>

// ---------------------------------------------------------------------------
// 3-state pair-HMM forward DP (smoothed max / logsumexp semiring).
//   V[i,j,0] = LSE_k( V[i-1,j-1,k] + th[i-1,j-1,0,k] )   (match)
//   V[i,j,1] = LSE_k( V[i-1,j  ,k] + th[i-1,j-1,1,k] )   (X)
//   V[i,j,2] = LSE_k( V[i  ,j-1,k] + th[i-1,j-1,2,k] )   (Y)
// out = LSE_k V[N,M,k]
//
// Structure: skewed band-pipeline wavefront.
//  - 24 bands of 64 rows, one 64-lane wave per band (one block each).
//  - lane r owns row 64b+r+1; at step t it computes column j = t-r+1.
//  - up/diag flow down-lane via __shfl_up (wave-synchronous, no barriers).
//  - band b-1's lane 63 streams its row V to global `bottom[b-1][j][3]` and
//    publishes progress every CHUNK columns (agent-scope release); band b's
//    lane 0 polls (acquire) once per CHUNK steps and prefetches `up` 2 steps
//    ahead. Producers never wait on consumers -> deadlock-free; 24 blocks
//    are trivially co-resident on 256 CUs.
// ---------------------------------------------------------------------------

#define MM      1536
#define HH      64
#define NBANDS  24            // 1536 / 64
#define NEG_INF (-1.0e8f)
#define CHUNK   16
#define TSTEPS  (MM + HH - 1) // 1599

__device__ __forceinline__ float lse3(float a0, float a1, float a2) {
    // max3/med3/min3 -> only 2 exps (the max term contributes exp(0)=1).
    float mx = fmaxf(fmaxf(a0, a1), a2);
    float mn = fminf(fminf(a0, a1), a2);
    float md = __builtin_amdgcn_fmed3f(a0, a1, a2);
    return mx + __logf(1.0f + __expf(mn - mx) + __expf(md - mx));
}

struct Theta9 { float v[9]; };

__global__ void init_progress_kernel(int* progress) {
    if (threadIdx.x < NBANDS) progress[threadIdx.x] = -1;
}

__global__ __launch_bounds__(64, 1)
void hmm_fwd_kernel(const float* __restrict__ theta, float* __restrict__ out,
                    float* __restrict__ bottom, int* __restrict__ progress)
{
    const int b = blockIdx.x;      // band
    const int r = threadIdx.x;     // lane = row within band
    const float* thp  = theta  + (size_t)(b * HH + r) * MM * 9;
    const float* bsrc = bottom + (size_t)(b - 1) * (MM + 1) * 3;  // valid iff b>0
    float*       bdst = bottom + (size_t)b       * (MM + 1) * 3;

    // V-state registers: diag = V[i-1,j-1], up = V[i-1,j], left = V[i,j-1]
    float d0, d1, d2, u0, u1, u2, l0, l1, l2;
    float qa0, qa1, qa2, qb0, qb1, qb2;   // lane-0 'up' prefetch pipeline

    d0 = d1 = d2 = (b == 0 && r == 0) ? 0.0f : NEG_INF;  // V[0,0]=0 border
    u0 = u1 = u2 = NEG_INF;
    l0 = l1 = l2 = NEG_INF;
    qa0 = qa1 = qa2 = NEG_INF;
    qb0 = qb1 = qb2 = NEG_INF;

    if (b > 0) {
        // wait until producer covers columns <= CHUNK+4, then preload up pipe
        while (__hip_atomic_load(&progress[b - 1], __ATOMIC_ACQUIRE,
                                 __HIP_MEMORY_SCOPE_AGENT) < (CHUNK + 4))
            __builtin_amdgcn_s_sleep(2);
        u0  = bsrc[1 * 3 + 0]; u1  = bsrc[1 * 3 + 1]; u2  = bsrc[1 * 3 + 2];
        qa0 = bsrc[2 * 3 + 0]; qa1 = bsrc[2 * 3 + 1]; qa2 = bsrc[2 * 3 + 2];
        qb0 = bsrc[3 * 3 + 0]; qb1 = bsrc[3 * 3 + 1]; qb2 = bsrc[3 * 3 + 2];
    }

    for (int t = 0; t < TSTEPS; ++t) {
        // chunked consumer sync: guarantee bottom[.., <= t+CHUNK+4] is valid
        if (b > 0 && (t & (CHUNK - 1)) == 0) {
            int need = t + CHUNK + 4;
            if (need > MM) need = MM;
            while (__hip_atomic_load(&progress[b - 1], __ATOMIC_ACQUIRE,
                                     __HIP_MEMORY_SCOPE_AGENT) < need)
                __builtin_amdgcn_s_sleep(2);
        }

        const int  c   = t - r;                         // theta column (j-1)
        const bool act = (c >= 0) && (c < MM);
        int cc = c < 0 ? 0 : (c >= MM ? MM - 1 : c);    // clamped for safety

        Theta9 th;
        __builtin_memcpy(&th, thp + (size_t)cc * 9, sizeof(Theta9));

        float n0 = lse3(d0 + th.v[0], d1 + th.v[1], d2 + th.v[2]);
        float n1 = lse3(u0 + th.v[3], u1 + th.v[4], u2 + th.v[5]);
        float n2 = lse3(l0 + th.v[6], l1 + th.v[7], l2 + th.v[8]);
        n0 = act ? n0 : NEG_INF;
        n1 = act ? n1 : NEG_INF;
        n2 = act ? n2 : NEG_INF;

        // producer: lane 63 streams band's bottom row, publishes every CHUNK
        if (b < NBANDS - 1 && r == HH - 1 && act) {
            const int j = c + 1;
            bdst[(size_t)j * 3 + 0] = n0;
            bdst[(size_t)j * 3 + 1] = n1;
            bdst[(size_t)j * 3 + 2] = n2;
            if ((j & (CHUNK - 1)) == 0)   // 1536 is a multiple of 16 -> covered
                __hip_atomic_store(&progress[b], j, __ATOMIC_RELEASE,
                                   __HIP_MEMORY_SCOPE_AGENT);
        }

        // rotate the wavefront state
        d0 = u0; d1 = u1; d2 = u2;
        float s0 = __shfl_up(n0, 1, 64);
        float s1 = __shfl_up(n1, 1, 64);
        float s2 = __shfl_up(n2, 1, 64);
        u0 = (r == 0) ? qa0 : s0;
        u1 = (r == 0) ? qa1 : s1;
        u2 = (r == 0) ? qa2 : s2;
        l0 = n0; l1 = n1; l2 = n2;

        // lane-0 'up' prefetch, 2 steps ahead (covered by chunk sync)
        qa0 = qb0; qa1 = qb1; qa2 = qb2;
        if (b > 0) {
            int c2 = t + 4;
            if (c2 > MM) c2 = MM;
            qb0 = bsrc[(size_t)c2 * 3 + 0];
            qb1 = bsrc[(size_t)c2 * 3 + 1];
            qb2 = bsrc[(size_t)c2 * 3 + 2];
        }
    }

    // lane 63 of the last band finished V[N,M] on the final step (held in l*)
    if (b == NBANDS - 1 && r == HH - 1)
        out[0] = lse3(l0, l1, l2);
}

extern "C" void kernel_launch(void* const* d_in, const int* in_sizes, int n_in,
                              void* d_out, int out_size, void* d_ws, size_t ws_size,
                              hipStream_t stream)
{
    const float* theta = (const float*)d_in[0];
    float* out = (float*)d_out;

    float* bottom   = (float*)d_ws;                         // 24*1537*3 floats
    int*   progress = (int*)((char*)d_ws +
                             (size_t)NBANDS * (MM + 1) * 3 * sizeof(float));

    // d_ws is poisoned 0xAA each call; make flags deterministically invalid.
    init_progress_kernel<<<1, 64, 0, stream>>>(progress);
    hmm_fwd_kernel<<<NBANDS, HH, 0, stream>>>(theta, out, bottom, progress);
}

// Round 3
// 1436.180 us; speedup vs baseline: 2.5467x; 2.5467x over previous
//
#include <hip/hip_runtime.h>

// ---------------------------------------------------------------------------
// 3-state pair-HMM forward DP (logsumexp semiring), skewed band pipeline.
//   24 bands x 64 rows, one 64-lane wave per band. Lane r owns row 64b+r+1,
//   at step t computes column j = (t - r) + 1. up/diag flow via __shfl_up.
//   Band handoff through global `bottom` rows + agent-scope progress flags.
// Round-2/3: register double-buffered BATCH prefetch of theta (36 B/col) and
//   the bottom-row feed, one 8-column block ahead, to break the per-column
//   serial HBM-latency chain (round 1: 3657 us, VALUBusy 0.21%). Math in
//   log2 domain via __builtin_amdgcn_exp2f / __builtin_amdgcn_logf
//   (v_exp_f32 / v_log_f32), *ln2 once at the end.
// ---------------------------------------------------------------------------

#define MM 1536
#define HH 64
#define NB 24
#define U  8
#define NBLK 200                    // 200*8 = 1600 >= MM+HH-1 = 1599 steps
#define LOG2E 1.4426950408889634f
#define LN2   0.6931471805599453f
#define NEG2  (-1.4426950408889634e8f)   // (-1e8) * LOG2E (log2-domain -inf)

struct T9 { float v[9]; };
struct F3 { float v[3]; };

__device__ __forceinline__ float lse3_2(float a, float b, float c) {
    // log2-domain LSE of 3: max3 + med3 + min3 (hw ops), 2 exp2 + 1 log2.
    float mx = fmaxf(fmaxf(a, b), c);
    float mn = fminf(fminf(a, b), c);
    float md = __builtin_amdgcn_fmed3f(a, b, c);
    return mx + __builtin_amdgcn_logf(1.0f + __builtin_amdgcn_exp2f(mn - mx)
                                           + __builtin_amdgcn_exp2f(md - mx));
}

__global__ void init_progress_kernel(int* progress) {
    if (threadIdx.x < NB) progress[threadIdx.x] = -1;
}

__global__ __launch_bounds__(64, 1)
void hmm_fwd_kernel(const float* __restrict__ theta, float* __restrict__ out,
                    float* __restrict__ bottom, int* __restrict__ progress)
{
    const int b    = blockIdx.x;
    const int lane = threadIdx.x;
    const float* __restrict__ thp = theta + (size_t)(b * HH + lane) * (MM * 9);
    const float* __restrict__ bsrc =
        bottom + (size_t)(b > 0 ? b - 1 : 0) * ((MM + 1) * 3);
    float* __restrict__ bdst = bottom + (size_t)b * ((MM + 1) * 3);

    T9 thA[U], thB[U];      // theta double buffer (8 cols x 9 floats each)
    F3 fdA[U], fdB[U];      // lane-0 'up' feed double buffer

    float d0, d1, d2, l0, l1, l2, s0, s1, s2, res0, res1, res2;
    d0 = d1 = d2 = (b == 0 && lane == 0) ? 0.0f : NEG2;   // V[0,0] = 0 border
    l0 = l1 = l2 = NEG2;
    s0 = s1 = s2 = NEG2;
    res0 = res1 = res2 = NEG2;

    #pragma unroll
    for (int k = 0; k < U; ++k) {
        fdA[k].v[0] = fdA[k].v[1] = fdA[k].v[2] = NEG2;
        fdB[k].v[0] = fdB[k].v[1] = fdB[k].v[2] = NEG2;
    }

    // pre-loop sync: covers prime (j<=8) + block-0 batch (j<=16) + block-1 (j<=24)
    if (b > 0) {
        while (__hip_atomic_load(&progress[b - 1], __ATOMIC_ACQUIRE,
                                 __HIP_MEMORY_SCOPE_AGENT) < 24)
            __builtin_amdgcn_s_sleep(2);
    }

    // prime block 0 into the A buffers
    #pragma unroll
    for (int k = 0; k < U; ++k) {
        int c = k - lane; c = c < 0 ? 0 : c;     // clamped; inactive cols masked
        __builtin_memcpy(&thA[k], thp + (size_t)c * 9, 36);
        if (b > 0)
            __builtin_memcpy(&fdA[k], bsrc + (size_t)(k + 1) * 3, 12);
    }

    auto block_body = [&](int T, T9 (&cur)[U], T9 (&nxt)[U],
                          F3 (&fcur)[U], F3 (&fnxt)[U]) {
        const int t0 = T * U;

        // consumer poll (even blocks): guarantee feed cols through t0+24
        if (b > 0 && T > 0 && (T & 1) == 0) {
            int need = t0 + 24; if (need > MM) need = MM;
            while (__hip_atomic_load(&progress[b - 1], __ATOMIC_ACQUIRE,
                                     __HIP_MEMORY_SCOPE_AGENT) < need)
                __builtin_amdgcn_s_sleep(2);
        }

        // batch-prefetch block T+1 (issue-and-forget; consumed one block later)
        #pragma unroll
        for (int k = 0; k < U; ++k) {
            int cn = t0 + U + k - lane;
            cn = cn < 0 ? 0 : (cn > MM - 1 ? MM - 1 : cn);
            __builtin_memcpy(&nxt[k], thp + (size_t)cn * 9, 36);
        }
        if (b > 0) {
            #pragma unroll
            for (int k = 0; k < U; ++k) {
                int jn = t0 + U + k + 1; if (jn > MM) jn = MM;
                __builtin_memcpy(&fnxt[k], bsrc + (size_t)jn * 3, 12);
            }
        }

        // compute 8 columns from the current buffers
        #pragma unroll
        for (int k = 0; k < U; ++k) {
            const int c = t0 + k - lane;
            const bool act = ((unsigned)c < (unsigned)MM);

            float u0 = (lane == 0) ? fcur[k].v[0] : s0;
            float u1 = (lane == 0) ? fcur[k].v[1] : s1;
            float u2 = (lane == 0) ? fcur[k].v[2] : s2;

            float aa0 = fmaf(cur[k].v[0], LOG2E, d0);
            float aa1 = fmaf(cur[k].v[1], LOG2E, d1);
            float aa2 = fmaf(cur[k].v[2], LOG2E, d2);
            float bb0 = fmaf(cur[k].v[3], LOG2E, u0);
            float bb1 = fmaf(cur[k].v[4], LOG2E, u1);
            float bb2 = fmaf(cur[k].v[5], LOG2E, u2);
            float cc0 = fmaf(cur[k].v[6], LOG2E, l0);
            float cc1 = fmaf(cur[k].v[7], LOG2E, l1);
            float cc2 = fmaf(cur[k].v[8], LOG2E, l2);

            float n0 = lse3_2(aa0, aa1, aa2);
            float n1 = lse3_2(bb0, bb1, bb2);
            float n2 = lse3_2(cc0, cc1, cc2);
            n0 = act ? n0 : NEG2;
            n1 = act ? n1 : NEG2;
            n2 = act ? n2 : NEG2;

            // producer: lane 63 streams this band's bottom row
            if (b < NB - 1 && lane == HH - 1 && act) {
                const int j = c + 1;
                bdst[(size_t)j * 3 + 0] = n0;
                bdst[(size_t)j * 3 + 1] = n1;
                bdst[(size_t)j * 3 + 2] = n2;
            }

            // capture V[N,M] (c == MM-1 on lane 63 of band NB-1)
            const bool fin = (c == MM - 1);
            res0 = fin ? n0 : res0;
            res1 = fin ? n1 : res1;
            res2 = fin ? n2 : res2;

            // rotate wavefront state
            d0 = u0; d1 = u1; d2 = u2;
            s0 = __shfl_up(n0, 1, 64);
            s1 = __shfl_up(n1, 1, 64);
            s2 = __shfl_up(n2, 1, 64);
            l0 = n0; l1 = n1; l2 = n2;
        }

        // publish progress every 2 blocks (release; batch loads are 8 cols old
        // by now so the vmcnt(0) fence drain is cheap)
        if (b < NB - 1 && lane == HH - 1 && (T & 1) == 1) {
            int val = t0 - 55;                 // j_last = (t0+7) - 63 + 1
            if (val >= 1) {
                if (val > MM) val = MM;
                __hip_atomic_store(&progress[b], val, __ATOMIC_RELEASE,
                                   __HIP_MEMORY_SCOPE_AGENT);
            }
        }
    };

    for (int T2 = 0; T2 < NBLK; T2 += 2) {
        block_body(T2,     thA, thB, fdA, fdB);
        block_body(T2 + 1, thB, thA, fdB, fdA);
    }

    if (b == NB - 1 && lane == HH - 1)
        out[0] = LN2 * lse3_2(res0, res1, res2);
}

extern "C" void kernel_launch(void* const* d_in, const int* in_sizes, int n_in,
                              void* d_out, int out_size, void* d_ws, size_t ws_size,
                              hipStream_t stream)
{
    const float* theta = (const float*)d_in[0];
    float* out = (float*)d_out;

    float* bottom   = (float*)d_ws;                       // 24*1537*3 floats
    int*   progress = (int*)((char*)d_ws +
                             (size_t)NB * (MM + 1) * 3 * sizeof(float));

    init_progress_kernel<<<1, 64, 0, stream>>>(progress);
    hmm_fwd_kernel<<<NB, HH, 0, stream>>>(theta, out, bottom, progress);
}

// Round 4
// 1419.215 us; speedup vs baseline: 2.5771x; 1.0120x over previous
//
#include <hip/hip_runtime.h>

// ---------------------------------------------------------------------------
// 3-state pair-HMM forward DP (logsumexp semiring), skewed band pipeline.
//   24 bands x 64 rows, one 64-lane wave per band. Lane r owns row 64b+r+1,
//   at step t computes column j = (t - r) + 1. up/diag flow via __shfl_up.
//   Band handoff through global `bottom` rows + agent-scope progress flags.
// R4: round 3 measured 906 cy/step == one HBM latency per column: the
//   compiler sank the "prefetch" loads to their uses (VGPR_Count 136 < the
//   144 floats of the two theta buffers). Fix: __builtin_amdgcn_sched_barrier(0)
//   after the batch-prefetch region pins the loads one full block ahead of
//   their consumption, making vmcnt cover ~900 cy of load latency with the
//   previous block's compute.
// ---------------------------------------------------------------------------

#define MM 1536
#define HH 64
#define NB 24
#define U  8
#define NBLK 200                    // 200*8 = 1600 >= MM+HH-1 = 1599 steps
#define LOG2E 1.4426950408889634f
#define LN2   0.6931471805599453f
#define NEG2  (-1.4426950408889634e8f)   // (-1e8) * LOG2E (log2-domain -inf)

struct T9 { float v[9]; };
struct F3 { float v[3]; };

__device__ __forceinline__ float lse3_2(float a, float b, float c) {
    // log2-domain LSE of 3: max3 + med3 + min3 (hw ops), 2 exp2 + 1 log2.
    float mx = fmaxf(fmaxf(a, b), c);
    float mn = fminf(fminf(a, b), c);
    float md = __builtin_amdgcn_fmed3f(a, b, c);
    return mx + __builtin_amdgcn_logf(1.0f + __builtin_amdgcn_exp2f(mn - mx)
                                           + __builtin_amdgcn_exp2f(md - mx));
}

__global__ void init_progress_kernel(int* progress) {
    if (threadIdx.x < NB) progress[threadIdx.x] = -1;
}

__global__ __launch_bounds__(64, 1)
void hmm_fwd_kernel(const float* __restrict__ theta, float* __restrict__ out,
                    float* __restrict__ bottom, int* __restrict__ progress)
{
    const int b    = blockIdx.x;
    const int lane = threadIdx.x;
    const float* __restrict__ thp = theta + (size_t)(b * HH + lane) * (MM * 9);
    const float* __restrict__ bsrc =
        bottom + (size_t)(b > 0 ? b - 1 : 0) * ((MM + 1) * 3);
    float* __restrict__ bdst = bottom + (size_t)b * ((MM + 1) * 3);

    T9 thA[U], thB[U];      // theta double buffer (8 cols x 9 floats each)
    F3 fdA[U], fdB[U];      // lane-0 'up' feed double buffer

    float d0, d1, d2, l0, l1, l2, s0, s1, s2, res0, res1, res2;
    d0 = d1 = d2 = (b == 0 && lane == 0) ? 0.0f : NEG2;   // V[0,0] = 0 border
    l0 = l1 = l2 = NEG2;
    s0 = s1 = s2 = NEG2;
    res0 = res1 = res2 = NEG2;

    #pragma unroll
    for (int k = 0; k < U; ++k) {
        fdA[k].v[0] = fdA[k].v[1] = fdA[k].v[2] = NEG2;
        fdB[k].v[0] = fdB[k].v[1] = fdB[k].v[2] = NEG2;
    }

    // pre-loop sync: covers prime (j<=8) + block-0 batch (j<=16) + block-1 (j<=24)
    if (b > 0) {
        while (__hip_atomic_load(&progress[b - 1], __ATOMIC_ACQUIRE,
                                 __HIP_MEMORY_SCOPE_AGENT) < 24)
            __builtin_amdgcn_s_sleep(2);
    }

    // prime block 0 into the A buffers
    #pragma unroll
    for (int k = 0; k < U; ++k) {
        int c = k - lane; c = c < 0 ? 0 : c;     // clamped; inactive cols masked
        __builtin_memcpy(&thA[k], thp + (size_t)c * 9, 36);
        if (b > 0)
            __builtin_memcpy(&fdA[k], bsrc + (size_t)(k + 1) * 3, 12);
    }

    auto block_body = [&](int T, T9 (&cur)[U], T9 (&nxt)[U],
                          F3 (&fcur)[U], F3 (&fnxt)[U]) {
        const int t0 = T * U;

        // consumer poll (even blocks): guarantee feed cols through t0+24
        if (b > 0 && T > 0 && (T & 1) == 0) {
            int need = t0 + 24; if (need > MM) need = MM;
            while (__hip_atomic_load(&progress[b - 1], __ATOMIC_ACQUIRE,
                                     __HIP_MEMORY_SCOPE_AGENT) < need)
                __builtin_amdgcn_s_sleep(2);
        }

        // batch-prefetch block T+1 (issue-and-forget; consumed one block later)
        #pragma unroll
        for (int k = 0; k < U; ++k) {
            int cn = t0 + U + k - lane;
            cn = cn < 0 ? 0 : (cn > MM - 1 ? MM - 1 : cn);
            __builtin_memcpy(&nxt[k], thp + (size_t)cn * 9, 36);
        }
        if (b > 0) {
            #pragma unroll
            for (int k = 0; k < U; ++k) {
                int jn = t0 + U + k + 1; if (jn > MM) jn = MM;
                __builtin_memcpy(&fnxt[k], bsrc + (size_t)jn * 3, 12);
            }
        }

        // ---- pin the prefetch: nothing may cross this point ----
        __builtin_amdgcn_sched_barrier(0);

        // compute 8 columns from the current buffers
        #pragma unroll
        for (int k = 0; k < U; ++k) {
            const int c = t0 + k - lane;
            const bool act = ((unsigned)c < (unsigned)MM);

            float u0 = (lane == 0) ? fcur[k].v[0] : s0;
            float u1 = (lane == 0) ? fcur[k].v[1] : s1;
            float u2 = (lane == 0) ? fcur[k].v[2] : s2;

            float aa0 = fmaf(cur[k].v[0], LOG2E, d0);
            float aa1 = fmaf(cur[k].v[1], LOG2E, d1);
            float aa2 = fmaf(cur[k].v[2], LOG2E, d2);
            float bb0 = fmaf(cur[k].v[3], LOG2E, u0);
            float bb1 = fmaf(cur[k].v[4], LOG2E, u1);
            float bb2 = fmaf(cur[k].v[5], LOG2E, u2);
            float cc0 = fmaf(cur[k].v[6], LOG2E, l0);
            float cc1 = fmaf(cur[k].v[7], LOG2E, l1);
            float cc2 = fmaf(cur[k].v[8], LOG2E, l2);

            float n0 = lse3_2(aa0, aa1, aa2);
            float n1 = lse3_2(bb0, bb1, bb2);
            float n2 = lse3_2(cc0, cc1, cc2);
            n0 = act ? n0 : NEG2;
            n1 = act ? n1 : NEG2;
            n2 = act ? n2 : NEG2;

            // producer: lane 63 streams this band's bottom row
            if (b < NB - 1 && lane == HH - 1 && act) {
                const int j = c + 1;
                bdst[(size_t)j * 3 + 0] = n0;
                bdst[(size_t)j * 3 + 1] = n1;
                bdst[(size_t)j * 3 + 2] = n2;
            }

            // capture V[N,M] (c == MM-1 on lane 63 of band NB-1)
            const bool fin = (c == MM - 1);
            res0 = fin ? n0 : res0;
            res1 = fin ? n1 : res1;
            res2 = fin ? n2 : res2;

            // rotate wavefront state
            d0 = u0; d1 = u1; d2 = u2;
            s0 = __shfl_up(n0, 1, 64);
            s1 = __shfl_up(n1, 1, 64);
            s2 = __shfl_up(n2, 1, 64);
            l0 = n0; l1 = n1; l2 = n2;
        }

        // publish progress every 2 blocks (release; batch loads are ~1 block
        // old by now so the vmcnt(0) fence drain is cheap)
        if (b < NB - 1 && lane == HH - 1 && (T & 1) == 1) {
            int val = t0 - 55;                 // j_last = (t0+7) - 63 + 1
            if (val >= 1) {
                if (val > MM) val = MM;
                __hip_atomic_store(&progress[b], val, __ATOMIC_RELEASE,
                                   __HIP_MEMORY_SCOPE_AGENT);
            }
        }
    };

    for (int T2 = 0; T2 < NBLK; T2 += 2) {
        block_body(T2,     thA, thB, fdA, fdB);
        block_body(T2 + 1, thB, thA, fdB, fdA);
    }

    if (b == NB - 1 && lane == HH - 1)
        out[0] = LN2 * lse3_2(res0, res1, res2);
}

extern "C" void kernel_launch(void* const* d_in, const int* in_sizes, int n_in,
                              void* d_out, int out_size, void* d_ws, size_t ws_size,
                              hipStream_t stream)
{
    const float* theta = (const float*)d_in[0];
    float* out = (float*)d_out;

    float* bottom   = (float*)d_ws;                       // 24*1537*3 floats
    int*   progress = (int*)((char*)d_ws +
                             (size_t)NB * (MM + 1) * 3 * sizeof(float));

    init_progress_kernel<<<1, 64, 0, stream>>>(progress);
    hmm_fwd_kernel<<<NB, HH, 0, stream>>>(theta, out, bottom, progress);
}